// Round 1
// baseline (400.832 us; speedup 1.0000x reference)
//
#include <hip/hip_runtime.h>
#include <stdint.h>

// ---------------------------------------------------------------------------
// DkNN round 5: 256x256-tile 8-phase deep-pipelined MFMA GEMM (T2+T3+T4+T5).
//  - 8 waves (2M x 4N), BK=64, 12 K-tiles (3 split-bf16 passes x 256).
//  - double-buffered 128 KiB LDS, XOR chunk swizzle (0 bank conflicts).
//  - counted s_waitcnt vmcnt(6): 3 half-tiles in flight across barriers;
//    one half-tile (2x global_load_lds dwordx4) issued per phase.
//  - s_setprio(1) around each 16-MFMA cluster.
//  - bijective XCD swizzle (nwg=1564 not divisible by 8), m-fastest within
//    an XCD slice so the 4 m-blocks of one n-tile share that XCD's L2.
// prep_all / classify unchanged from round 4.
// ---------------------------------------------------------------------------

typedef __attribute__((ext_vector_type(8))) short short8;   // 8 bf16 = 4 VGPR
typedef __attribute__((ext_vector_type(4))) float float4v;  // MFMA C/D

#define BAR()   asm volatile("s_barrier" ::: "memory")
#define LGKM0() asm volatile("s_waitcnt lgkmcnt(0)" ::: "memory")
#define VMC6()  asm volatile("s_waitcnt vmcnt(6)" ::: "memory")
#define VMC0()  asm volatile("s_waitcnt vmcnt(0)" ::: "memory")

static __device__ __forceinline__ unsigned short bf16_rn(float f) {
    unsigned int u = __float_as_uint(f);
    unsigned int r = (u + 0x7FFFu + ((u >> 16) & 1u)) >> 16;
    return (unsigned short)r;
}

static __device__ __forceinline__ void gload_lds16(const void* g, void* l) {
    __builtin_amdgcn_global_load_lds(
        (const __attribute__((address_space(1))) unsigned int*)g,
        (__attribute__((address_space(3))) unsigned int*)l, 16, 0, 0);
}

// Fused prep: blocks [0, Np/4) convert train rows (4/block); blocks
// [Np/4, Np/4+Mp) prep one query row each (normalize, center, hi/lo, q2, gkey).
__global__ void prep_all(const float* __restrict__ X, const float* __restrict__ x,
                         const float* __restrict__ center,
                         unsigned short* __restrict__ Bh, unsigned short* __restrict__ Bl,
                         float* __restrict__ xn2,
                         unsigned short* __restrict__ Ah, unsigned short* __restrict__ Al,
                         float* __restrict__ q2, unsigned long long* __restrict__ gkey,
                         int nb_train, int Np, int B, int Mp) {
    const int tid = threadIdx.x;
    const int tb = Np >> 2;
    if (blockIdx.x < (unsigned)tb) {
        // ---- train side: 4 rows per block, one wave each ----
        int row = blockIdx.x * 4 + (tid >> 6);
        int lane = tid & 63;
        if (row >= nb_train) {
            ushort4 z = make_ushort4(0, 0, 0, 0);
            *(ushort4*)(Bh + (size_t)row * 256 + lane * 4) = z;
            *(ushort4*)(Bl + (size_t)row * 256 + lane * 4) = z;
            if (lane == 0) xn2[row] = 3.0e38f;
            return;
        }
        float4 v = ((const float4*)(X + (size_t)row * 256))[lane];
        ushort4 h, l;
        h.x = bf16_rn(v.x); l.x = bf16_rn(v.x - __uint_as_float((unsigned)h.x << 16));
        h.y = bf16_rn(v.y); l.y = bf16_rn(v.y - __uint_as_float((unsigned)h.y << 16));
        h.z = bf16_rn(v.z); l.z = bf16_rn(v.z - __uint_as_float((unsigned)h.z << 16));
        h.w = bf16_rn(v.w); l.w = bf16_rn(v.w - __uint_as_float((unsigned)h.w << 16));
        *(ushort4*)(Bh + (size_t)row * 256 + lane * 4) = h;
        *(ushort4*)(Bl + (size_t)row * 256 + lane * 4) = l;
        float ss = v.x * v.x + v.y * v.y + v.z * v.z + v.w * v.w;
        #pragma unroll
        for (int s = 1; s < 64; s <<= 1) ss += __shfl_xor(ss, s);
        if (lane == 0) xn2[row] = ss;
        return;
    }
    // ---- query side: one row per block, 256 threads (d=256) ----
    int row = blockIdx.x - tb;
    if (row >= Mp) return;
    if (tid == 0) gkey[row] = ~0ULL;
    if (row >= B) {
        Ah[(size_t)row * 256 + tid] = 0;
        Al[(size_t)row * 256 + tid] = 0;
        if (tid == 0) q2[row] = 0.0f;
        return;
    }
    float v = x[(size_t)row * 256 + tid];
    float ss = v * v;
    #pragma unroll
    for (int s = 1; s < 64; s <<= 1) ss += __shfl_xor(ss, s);
    __shared__ float partial[4];
    __shared__ float partial2[4];
    if ((tid & 63) == 0) partial[tid >> 6] = ss;
    __syncthreads();
    float tot = partial[0] + partial[1] + partial[2] + partial[3];
    float inv = 1.0f / sqrtf(tot);
    float val = v * inv - center[tid];
    unsigned short hb = bf16_rn(val);
    float hf = __uint_as_float((unsigned int)hb << 16);
    unsigned short lb = bf16_rn(val - hf);
    Ah[(size_t)row * 256 + tid] = hb;
    Al[(size_t)row * 256 + tid] = lb;
    float ss2 = val * val;
    #pragma unroll
    for (int s = 1; s < 64; s <<= 1) ss2 += __shfl_xor(ss2, s);
    if ((tid & 63) == 0) partial2[tid >> 6] = ss2;
    __syncthreads();
    if (tid == 0) q2[row] = partial2[0] + partial2[1] + partial2[2] + partial2[3];
}

// ---------------------------------------------------------------------------
// 256x256 tile, 8 waves (wm=wave>>2 in {0,1} -> 128 M-rows; wn=wave&3 -> 64
// N-cols). Per K-tile (BK=64): 4 phases, each = {ds_read subtile || issue one
// half-tile gload_lds -> bar -> lgkm(0) -> setprio(1) 16xMFMA setprio(0) ->
// bar}. Quadrant snake (a0b0, a0b1, a1b1, a1b0) so regions retire in order:
//   issue plan (K-tile m): q1: A1(m+1)->buf^1 | q3: B0(m+2)->buf |
//                          q4: B1(m+2), A0(m+2)->buf
//   vmcnt(6) at q4 => the 3 newest half-tiles may fly; K-tile m+1 resident.
// ---------------------------------------------------------------------------
__global__ __launch_bounds__(512, 2) void mfma_tile(
    const unsigned short* __restrict__ Adata,  // [Ah | Al], each Mp*256
    const unsigned short* __restrict__ Bdata,  // [Bh | Bl], each Np*256
    const float* __restrict__ q2, const float* __restrict__ xn2,
    unsigned long long* __restrict__ gkey,
    int Mp, int Np, int B, int ntiles)
{
    __shared__ unsigned short As[2][256 * 64];   // [row][chunk ^ (row&7)]
    __shared__ unsigned short Bs[2][256 * 64];

    // bijective XCD swizzle (m204): nwg = ntiles*4, m fastest within slice
    const int nwg  = ntiles * 4;
    const int orig = blockIdx.x;
    const int xcd  = orig & 7;
    const int qq   = nwg >> 3, rr = nwg & 7;
    const int wgid = (xcd < rr ? xcd * (qq + 1) : rr * (qq + 1) + (xcd - rr) * qq)
                   + (orig >> 3);
    const int mtile = (wgid & 3) * 256;
    const int ntile = (wgid >> 2) * 256;

    const int tid  = threadIdx.x;
    const int wave = tid >> 6;
    const int lane = tid & 63;
    const size_t APROD = (size_t)Mp * 256;
    const size_t BPROD = (size_t)Np * 256;

    // ---- staging addressing: per round, 512 threads cover 64 rows x 8 chunks
    const int    srow = lane >> 3;                       // row within 8-row seg
    const int    schk = ((lane & 7) ^ srow) * 8;         // pre-swizzled chunk
    const size_t aoff = (size_t)(mtile + wave * 8 + srow) * 256 + schk;
    const size_t boff = (size_t)(ntile + wave * 8 + srow) * 256 + schk;
    const int    dwav = wave * 512;                      // ushorts

    auto stageA = [&](int tt, int hh) {                  // half-tile hh of K-tile tt
        if (tt >= 12) return;
        const int p = tt >> 2, sk = (tt & 3) * 64;
        const unsigned short* src = Adata + (p == 1 ? APROD : 0)
                                  + aoff + (size_t)hh * (128 * 256) + sk;
        unsigned short* dst = &As[tt & 1][hh * 8192 + dwav];
        gload_lds16(src, dst);
        gload_lds16(src + 64 * 256, dst + 4096);
    };
    auto stageB = [&](int tt, int hh) {
        if (tt >= 12) return;
        const int p = tt >> 2, sk = (tt & 3) * 64;
        const unsigned short* src = Bdata + (p == 2 ? BPROD : 0)
                                  + boff + (size_t)hh * (128 * 256) + sk;
        unsigned short* dst = &Bs[tt & 1][hh * 8192 + dwav];
        gload_lds16(src, dst);
        gload_lds16(src + 64 * 256, dst + 4096);
    };

    // ---- compute role
    const int wm = wave >> 2, wn = wave & 3;
    const int lrow = lane & 15, kseg = lane >> 4, sw = lane & 7;
    const int AM = wm * 128, BN = wn * 64;

    float4v acc[8][4];
    #pragma unroll
    for (int i = 0; i < 8; ++i)
        #pragma unroll
        for (int j = 0; j < 4; ++j)
            acc[i][j] = (float4v){0.f, 0.f, 0.f, 0.f};

    short8 a[4][2], bA[2][2], bB[2][2];
    const unsigned short* Ab;
    const unsigned short* Bb;

#define RDA(h) { _Pragma("unroll") for (int i = 0; i < 4; ++i) \
                 _Pragma("unroll") for (int t = 0; t < 2; ++t) \
    a[i][t] = *(const short8*)&Ab[(AM + (h)*64 + i*16 + lrow)*64 + (((t*4+kseg)^sw)*8)]; }
#define RDB(dst, j0) { _Pragma("unroll") for (int j = 0; j < 2; ++j) \
                       _Pragma("unroll") for (int t = 0; t < 2; ++t) \
    dst[j][t] = *(const short8*)&Bb[(BN + ((j0)+j)*16 + lrow)*64 + (((t*4+kseg)^sw)*8)]; }
#define MF(h, bf, j0) { _Pragma("unroll") for (int t = 0; t < 2; ++t) \
                        _Pragma("unroll") for (int i = 0; i < 4; ++i) \
                        _Pragma("unroll") for (int j = 0; j < 2; ++j) \
    acc[(h)*4+i][(j0)+j] = __builtin_amdgcn_mfma_f32_16x16x32_bf16( \
        a[i][t], bf[j][t], acc[(h)*4+i][(j0)+j], 0, 0, 0); }

    // ---- prologue: K0 fully + K1 {B0,B1,A0}; A1(K1) is issued at m=0 q1.
    stageA(0, 0); stageA(0, 1); stageB(0, 0); stageB(0, 1);
    stageB(1, 0); stageB(1, 1); stageA(1, 0);
    VMC6(); BAR();

    int cur = 0;
    for (int m = 0; m < 12; ++m) {
        Ab = As[cur]; Bb = Bs[cur];
        // -- q1: quadrant (a0,b0)
        RDA(0); RDB(bA, 0);
        stageA(m + 1, 1);                       // A1 of m+1 -> buf^1
        BAR(); LGKM0();
        __builtin_amdgcn_s_setprio(1); MF(0, bA, 0); __builtin_amdgcn_s_setprio(0);
        BAR();
        // -- q2: quadrant (a0,b1)
        RDB(bB, 2);
        BAR(); LGKM0();
        __builtin_amdgcn_s_setprio(1); MF(0, bB, 2); __builtin_amdgcn_s_setprio(0);
        BAR();
        // -- q3: quadrant (a1,b1)   (B-low of buf retired at q2-end)
        RDA(1);
        stageB(m + 2, 0);                       // B0 of m+2 -> buf
        BAR(); LGKM0();
        __builtin_amdgcn_s_setprio(1); MF(1, bB, 2); __builtin_amdgcn_s_setprio(0);
        BAR();
        // -- q4: quadrant (a1,b0)   (A of buf retired at q3-end)
        stageB(m + 2, 1); stageA(m + 2, 0);     // B1, A0 of m+2 -> buf
        BAR();
        __builtin_amdgcn_s_setprio(1); MF(1, bA, 0); __builtin_amdgcn_s_setprio(0);
        if (m < 10) { VMC6(); } else { VMC0(); }   // tail: guards skip issues
        BAR();
        cur ^= 1;
    }
#undef RDA
#undef RDB
#undef MF

    // ---- epilogue: score = q2[m] - 2*dot + xn2[t]; packed argmin ----
    unsigned long long* skey = (unsigned long long*)&As[0][0];
    if (tid < 256) skey[tid] = ~0ULL;
    __syncthreads();

    float xnv[4];
    #pragma unroll
    for (int j = 0; j < 4; ++j)
        xnv[j] = xn2[ntile + BN + j * 16 + lrow];   // pads hold 3e38

    #pragma unroll
    for (int mi = 0; mi < 8; ++mi) {
        #pragma unroll
        for (int r = 0; r < 4; ++r) {
            const int lm = AM + mi * 16 + kseg * 4 + r;   // block-local query
            const int gm = mtile + lm;
            unsigned long long best = ~0ULL;
            if (gm < B) {
                float q2v = q2[gm];
                #pragma unroll
                for (int j = 0; j < 4; ++j) {
                    int t_ = ntile + BN + j * 16 + lrow;
                    float sc = fmaxf(q2v - 2.0f * acc[mi][j][r] + xnv[j], 0.0f);
                    unsigned long long key =
                        ((unsigned long long)__float_as_uint(sc) << 32) | (unsigned int)t_;
                    best = (key < best) ? key : best;
                }
            }
            #pragma unroll
            for (int sft = 1; sft < 16; sft <<= 1) {
                unsigned long long o = __shfl_xor(best, sft);
                best = (o < best) ? o : best;
            }
            if (lrow == 0 && gm < B) atomicMin(&skey[lm], best);
        }
    }
    __syncthreads();
    if (tid < 256) {
        int gm = mtile + tid;
        if (gm < B && skey[tid] != ~0ULL) atomicMin(gkey + gm, skey[tid]);
    }
}

// One wave per query: 75 gathers across lanes, ballot bincount, bisect p-values.
__global__ void classify(const unsigned long long* __restrict__ gkey,
                         const int* __restrict__ labels,
                         const int* __restrict__ nbr,
                         const int* __restrict__ cali,
                         float* __restrict__ out,
                         int knm1, int nb_cali, int B)
{
    int q = blockIdx.x * 4 + (threadIdx.x >> 6);
    int lane = threadIdx.x & 63;
    if (q >= B) return;
    int closest = (int)(gkey[q] & 0xFFFFFFFFULL);
    int K = knm1 + 1;   // 75
    int lbl0 = -1, lbl1 = -1;
    if (lane < K) {
        int idx = (lane == 0) ? closest : nbr[(size_t)closest * knm1 + (lane - 1)];
        lbl0 = labels[idx];
    }
    int j2 = lane + 64;
    if (j2 < K) {
        int idx = nbr[(size_t)closest * knm1 + (j2 - 1)];
        lbl1 = labels[idx];
    }
    int bestc = 0, bestp = -1;
    #pragma unroll
    for (int c = 0; c < 10; ++c) {
        int cnt = __popcll(__ballot(lbl0 == c)) + __popcll(__ballot(lbl1 == c));
        int v = K - cnt;
        int lo = 0, hi = nb_cali;
        while (lo < hi) {                 // bisect_left
            int mid = (lo + hi) >> 1;
            if (cali[mid] < v) lo = mid + 1; else hi = mid;
        }
        int p = nb_cali - lo;
        if (p > bestp) { bestp = p; bestc = c; }   // strict > == first-occurrence argmax
    }
    float pv = (float)bestp / (float)nb_cali;
    if (lane < 10)
        out[(size_t)q * 10 + lane] = (lane == bestc) ? pv : 0.0f;
}

extern "C" void kernel_launch(void* const* d_in, const int* in_sizes, int n_in,
                              void* d_out, int out_size, void* d_ws, size_t ws_size,
                              hipStream_t stream) {
    const float* x      = (const float*)d_in[0];
    const float* X      = (const float*)d_in[1];
    const float* center = (const float*)d_in[2];
    const int* labels   = (const int*)d_in[3];
    const int* nbr      = (const int*)d_in[4];
    const int* cali     = (const int*)d_in[5];
    float* out = (float*)d_out;

    const int d        = in_sizes[2];              // 256
    const int B        = in_sizes[0] / d;          // 1024
    const int nb_train = in_sizes[3];              // 100000
    const int knm1     = in_sizes[4] / nb_train;   // 74
    const int nb_cali  = in_sizes[5];              // 1000

    const int Mp = (B + 255) & ~255;               // 1024
    const int Np = (nb_train + 255) & ~255;        // 100096 = 391*256

    char* ws = (char*)d_ws;
    size_t off = 0;
    unsigned long long* gkey = (unsigned long long*)(ws + off); off += (size_t)Mp * 8;
    unsigned short* Adata = (unsigned short*)(ws + off); off += (size_t)Mp * 256 * 2 * 2;
    float* q2 = (float*)(ws + off); off += (size_t)Mp * 4;
    unsigned short* Bdata = (unsigned short*)(ws + off); off += (size_t)Np * 256 * 2 * 2;
    float* xn2 = (float*)(ws + off); off += (size_t)Np * 4;

    unsigned short* Ah = Adata;
    unsigned short* Al = Adata + (size_t)Mp * 256;
    unsigned short* Bh = Bdata;
    unsigned short* Bl = Bdata + (size_t)Np * 256;

    prep_all<<<Np / 4 + Mp, 256, 0, stream>>>(X, x, center, Bh, Bl, xn2,
                                              Ah, Al, q2, gkey,
                                              nb_train, Np, B, Mp);
    const int ntiles = Np / 256;                   // 391
    mfma_tile<<<ntiles * 4, 512, 0, stream>>>(
        Adata, Bdata, q2, xn2, gkey, Mp, Np, B, ntiles);
    classify<<<(B + 3) / 4, 256, 0, stream>>>(gkey, labels, nbr, cali, out,
                                              knm1, nb_cali, B);
}